// Round 2
// baseline (321.526 us; speedup 1.0000x reference)
//
#include <hip/hip_runtime.h>

#define NB 512
#define NG 100
#define NP 100
#define NE 128
#define NH 8

typedef __attribute__((ext_vector_type(8))) short short8;
typedef __attribute__((ext_vector_type(4))) short short4v;
typedef __attribute__((ext_vector_type(4))) float f32x4;

// LDS geometry: all bf16(short) row-major, XOR-swizzled per row.
// element (row,col) -> physical short offset: (row*STRIDE + col) ^ ((row&15)<<2)
// (<<2 shorts == <<3 bytes; all accesses are >=4-short aligned chunks or scalars)
#define SE_STRIDE 128
#define SK_STRIDE 128
#define SVT_STRIDE 112
#define SE_BASE 0
#define SK_BASE (100 * 128)                  // 12800 shorts
#define SVT_BASE (SK_BASE + 100 * 128)       // 25600 shorts
#define SMEM_SHORTS (SVT_BASE + 128 * 112)   // 39936 shorts = 79872 B
#define SMEM_BYTES (SMEM_SHORTS * 2 + 256 * 4)  // + sQ1[256] f32 = 80896 B

__device__ __forceinline__ short f2bf(float f) {
    union { float f; unsigned u; } v; v.f = f;
    unsigned r = v.u + 0x7FFFu + ((v.u >> 16) & 1u);
    return (short)(r >> 16);
}

__device__ __forceinline__ f32x4 mfma16(short4v a, short4v b, f32x4 c) {
#if __has_builtin(__builtin_amdgcn_mfma_f32_16x16x16_bf16)
    return __builtin_amdgcn_mfma_f32_16x16x16_bf16(a, b, c, 0, 0, 0);
#elif __has_builtin(__builtin_amdgcn_mfma_f32_16x16x16bf16_1k)
    return __builtin_amdgcn_mfma_f32_16x16x16bf16_1k(a, b, c, 0, 0, 0);
#else
    f32x4 d;
    asm volatile("v_mfma_f32_16x16x16_bf16 %0, %1, %2, %3"
                 : "=&v"(d) : "v"(a), "v"(b), "v"(c));
    return d;
#endif
}

__device__ __forceinline__ f32x4 mfma32(short8 a, short8 b, f32x4 c) {
    return __builtin_amdgcn_mfma_f32_16x16x32_bf16(a, b, c, 0, 0, 0);
}

// ---- prep: transpose weights to bf16 row-major [n][k] in ws ----
__global__ void prep_kernel(const float* __restrict__ Wq, const float* __restrict__ Wk,
                            const float* __restrict__ Wv, const float* __restrict__ Wc,
                            short* __restrict__ WqT2, short* __restrict__ WkT,
                            short* __restrict__ WvT, short* __restrict__ WcT)
{
    int idx = blockIdx.x * 256 + threadIdx.x;   // 65536 total
    int mat = idx >> 14;
    int e   = idx & 16383;
    int k = e >> 7, n = e & 127;
    float v;
    short* dst;
    if (mat == 0)      { v = Wq[(128 + k) * 128 + n]; dst = WqT2; }
    else if (mat == 1) { v = Wk[k * 128 + n];         dst = WkT;  }
    else if (mat == 2) { v = Wv[k * 128 + n];         dst = WvT;  }
    else               { v = Wc[k * 128 + n];         dst = WcT;  }
    dst[n * 128 + k] = f2bf(v);
}

// ---- fused main kernel: one block per batch, 7 waves, everything transposed ----
__global__ __launch_bounds__(448, 4)
void fused_kernel(const float* __restrict__ input1, const float* __restrict__ input2,
                  const float* __restrict__ rem, const float* __restrict__ mask,
                  const float* __restrict__ enc, const float* __restrict__ Wq,
                  const float* __restrict__ bc,
                  const short* __restrict__ WqT2, const short* __restrict__ WkT,
                  const short* __restrict__ WvT, const short* __restrict__ WcT,
                  float* __restrict__ out)
{
    extern __shared__ short smem[];
    float* sQ1 = (float*)(smem + SMEM_SHORTS);   // [2][128] q1 partials

    const int b    = blockIdx.x;
    const int tid  = threadIdx.x;
    const int wave = tid >> 6, lane = tid & 63;
    const int l16  = lane & 15, lh = lane >> 4;
    const int gt   = wave;                        // 7 waves, 7 g-tiles
    const int g    = gt * 16 + l16;
    const bool gok = (g < NG);
    const float NINF = -__builtin_inff();

    // ---------- Phase 0: stage enc -> sE (swizzled bf16), zero sVT pad, q1 ----------
    {
        const f32x4* e4 = (const f32x4*)(enc + (size_t)b * NP * NE);
        for (int idx = tid; idx < NP * 32; idx += 448) {
            int row = idx >> 5, c = idx & 31;
            f32x4 v = e4[idx];
            short4v h = { f2bf(v[0]), f2bf(v[1]), f2bf(v[2]), f2bf(v[3]) };
            int off = (row * SE_STRIDE + c * 4) ^ ((row & 15) << 2);
            *(short4v*)(smem + SE_BASE + off) = h;
        }
        // zero V^T cols 100..111 (never written afterwards)
        for (int idx = tid; idx < 128 * 3; idx += 448) {
            int row = idx / 3, c = 100 + (idx % 3) * 4;
            int off = (row * SVT_STRIDE + c) ^ ((row & 15) << 2);
            *(short4v*)(smem + SVT_BASE + off) = (short4v){0, 0, 0, 0};
        }
        // q1[n] = input1[b] . Wq[0:128, n] in two 64-k partials
        if (tid < 256) {
            int part = tid >> 7, n = tid & 127;
            const float* i1 = input1 + (size_t)b * NE + part * 64;
            const float* wq = Wq + (size_t)part * 64 * NE + n;
            float s = 0.f;
            #pragma unroll 8
            for (int k = 0; k < 64; ++k) s += i1[k] * wq[k * NE];
            sQ1[part * 128 + n] = s;
        }
    }
    __syncthreads();

    // ---------- Phase 2: K -> sK, V^T -> sVT (112 tile-tasks over 7 waves) ----------
    for (int t = wave; t < 112; t += 7) {
        int mat = (t >= 56);
        int tt  = mat ? t - 56 : t;
        int mt = tt >> 3, nt = tt & 7;
        const short* WT = mat ? WvT : WkT;
        int arow = mt * 16 + l16;
        bool aok = (arow < NP);
        f32x4 acc = {0.f, 0.f, 0.f, 0.f};
        #pragma unroll
        for (int kt = 0; kt < 8; ++kt) {
            short4v a = {0, 0, 0, 0};
            if (aok) {
                int off = (arow * SE_STRIDE + kt * 16 + lh * 4) ^ ((arow & 15) << 2);
                a = *(const short4v*)(smem + SE_BASE + off);
            }
            short4v w = *(const short4v*)(WT + (nt * 16 + l16) * NE + kt * 16 + lh * 4);
            acc = mfma16(a, w, acc);
        }
        if (!mat) {
            #pragma unroll
            for (int r = 0; r < 4; ++r) {
                int p = mt * 16 + lh * 4 + r;
                if (p < NP) {
                    int off = (p * SK_STRIDE + nt * 16 + l16) ^ ((p & 15) << 2);
                    smem[SK_BASE + off] = f2bf(acc[r]);
                }
            }
        } else {
            int vrow = nt * 16 + l16;          // k-dim 0..127
            int p0 = mt * 16 + lh * 4;
            if (p0 < NP) {                     // p0 in {..,96}: cols 96..99 valid
                short4v h = { f2bf(acc[0]), f2bf(acc[1]), f2bf(acc[2]), f2bf(acc[3]) };
                int off = (vrow * SVT_STRIDE + p0) ^ ((vrow & 15) << 2);
                *(short4v*)(smem + SVT_BASE + off) = h;
            }
        }
    }

    // ---------- Phase 1: Q^T into regs (x32), fold 1/sqrt(16), pack bf16 ----------
    short4v qb[8];
    {
        const float* xrow = input2 + ((size_t)b * NG + g) * NE;
        short8 xb[4];
        #pragma unroll
        for (int ks = 0; ks < 4; ++ks) {
            f32x4 v0 = {0.f,0.f,0.f,0.f}, v1 = {0.f,0.f,0.f,0.f};
            if (gok) {
                v0 = *(const f32x4*)(xrow + ks * 32 + lh * 8);
                v1 = *(const f32x4*)(xrow + ks * 32 + lh * 8 + 4);
            }
            xb[ks] = (short8){ f2bf(v0[0]), f2bf(v0[1]), f2bf(v0[2]), f2bf(v0[3]),
                               f2bf(v1[0]), f2bf(v1[1]), f2bf(v1[2]), f2bf(v1[3]) };
        }
        float remv = gok ? rem[(size_t)b * NG + g] : 0.f;
        #pragma unroll
        for (int nt = 0; nt < 8; ++nt) {
            f32x4 acc = {0.f, 0.f, 0.f, 0.f};
            #pragma unroll
            for (int ks = 0; ks < 4; ++ks) {
                short8 a = *(const short8*)(WqT2 + (nt * 16 + l16) * NE + ks * 32 + lh * 8);
                acc = mfma32(a, xb[ks], acc);
            }
            f32x4 q1a = *(const f32x4*)(sQ1 + nt * 16 + lh * 4);
            f32x4 q1b = *(const f32x4*)(sQ1 + 128 + nt * 16 + lh * 4);
            f32x4 wlv = *(const f32x4*)(Wq + 256 * NE + nt * 16 + lh * 4);
            short4v q;
            #pragma unroll
            for (int r = 0; r < 4; ++r)
                q[r] = f2bf(0.25f * (acc[r] + q1a[r] + q1b[r] + remv * wlv[r]));
            qb[nt] = q;
        }
    }

    // ---------- mask preload (latency hidden by barrier wait) ----------
    float mk[7][4];
    {
        const float* mrow = mask + ((size_t)b * NG + g) * NP;
        #pragma unroll
        for (int pt = 0; pt < 7; ++pt)
            #pragma unroll
            for (int r = 0; r < 4; ++r) {
                int p = pt * 16 + lh * 4 + r;
                mk[pt][r] = (gok && p < NP) ? mrow[p] : NINF;
            }
    }
    __syncthreads();

    // ---------- Phase 3: attention, all-register online path ----------
    short4v ocb[8];
    #pragma unroll
    for (int h = 0; h < NH; ++h) {
        f32x4 sc[7];
        #pragma unroll
        for (int pt = 0; pt < 7; ++pt) {
            int prow = pt * 16 + l16;
            int off = (prow * SK_STRIDE + h * 16 + lh * 4) ^ ((prow & 15) << 2);
            short4v kf = *(const short4v*)(smem + SK_BASE + off);
            f32x4 z = {0.f, 0.f, 0.f, 0.f};
            sc[pt] = mfma16(kf, qb[h], z);
        }
        float vals[7][4];
        float m = NINF;
        #pragma unroll
        for (int pt = 0; pt < 7; ++pt)
            #pragma unroll
            for (int r = 0; r < 4; ++r) {
                bool pv = (pt < 6) || (lh == 0);   // p < 100
                float v = pv ? sc[pt][r] + mk[pt][r] : NINF;
                vals[pt][r] = v;
                m = fmaxf(m, v);
            }
        m = fmaxf(m, __shfl_xor(m, 16));
        m = fmaxf(m, __shfl_xor(m, 32));
        float s = 0.f;
        #pragma unroll
        for (int pt = 0; pt < 7; ++pt)
            #pragma unroll
            for (int r = 0; r < 4; ++r) {
                float e = __expf(vals[pt][r] - m);
                vals[pt][r] = e; s += e;
            }
        s += __shfl_xor(s, 16);
        s += __shfl_xor(s, 32);
        float inv = 1.f / s;
        f32x4 o = {0.f, 0.f, 0.f, 0.f};
        #pragma unroll
        for (int pt = 0; pt < 7; ++pt) {
            short4v pb = { f2bf(vals[pt][0] * inv), f2bf(vals[pt][1] * inv),
                           f2bf(vals[pt][2] * inv), f2bf(vals[pt][3] * inv) };
            int vrow = h * 16 + l16;
            int off = (vrow * SVT_STRIDE + pt * 16 + lh * 4) ^ ((vrow & 15) << 2);
            short4v vf = *(const short4v*)(smem + SVT_BASE + off);
            o = mfma16(vf, pb, o);
        }
        ocb[h] = (short4v){ f2bf(o[0]), f2bf(o[1]), f2bf(o[2]), f2bf(o[3]) };
    }

    // ---------- Phase 4: Mh^T = Wc^T . oc^T + bc, fold 1/sqrt(128), pack ----------
    short4v mhb[8];
    #pragma unroll
    for (int nt = 0; nt < 8; ++nt) {
        f32x4 acc = {0.f, 0.f, 0.f, 0.f};
        #pragma unroll
        for (int kt = 0; kt < 8; ++kt) {
            short4v a = *(const short4v*)(WcT + (nt * 16 + l16) * NE + kt * 16 + lh * 4);
            acc = mfma16(a, ocb[kt], acc);
        }
        f32x4 bcv = *(const f32x4*)(bc + nt * 16 + lh * 4);
        mhb[nt] = (short4v){ f2bf((acc[0] + bcv[0]) * 0.08838834764831845f),
                             f2bf((acc[1] + bcv[1]) * 0.08838834764831845f),
                             f2bf((acc[2] + bcv[2]) * 0.08838834764831845f),
                             f2bf((acc[3] + bcv[3]) * 0.08838834764831845f) };
    }

    // ---------- Phase 5: pointer scores + tanh clip + softmax -> out ----------
    float vals2[7][4];
    #pragma unroll
    for (int pt = 0; pt < 7; ++pt) {
        int prow = pt * 16 + l16;
        f32x4 acc = {0.f, 0.f, 0.f, 0.f};
        #pragma unroll
        for (int kt = 0; kt < 8; ++kt) {
            int off = (prow * SE_STRIDE + kt * 16 + lh * 4) ^ ((prow & 15) << 2);
            short4v ef = *(const short4v*)(smem + SE_BASE + off);
            acc = mfma16(ef, mhb[kt], acc);
        }
        #pragma unroll
        for (int r = 0; r < 4; ++r) {
            bool pv = (pt < 6) || (lh == 0);
            float x = acc[r];                              // already scaled
            float th = 1.f - 2.f / (__expf(2.f * x) + 1.f);
            vals2[pt][r] = pv ? 10.f * th + mk[pt][r] : NINF;
        }
    }
    {
        float m = NINF;
        #pragma unroll
        for (int pt = 0; pt < 7; ++pt)
            #pragma unroll
            for (int r = 0; r < 4; ++r) m = fmaxf(m, vals2[pt][r]);
        m = fmaxf(m, __shfl_xor(m, 16));
        m = fmaxf(m, __shfl_xor(m, 32));
        float s = 0.f;
        #pragma unroll
        for (int pt = 0; pt < 7; ++pt)
            #pragma unroll
            for (int r = 0; r < 4; ++r) {
                float e = __expf(vals2[pt][r] - m);
                vals2[pt][r] = e; s += e;
            }
        s += __shfl_xor(s, 16);
        s += __shfl_xor(s, 32);
        float inv = 1.f / s;
        float* orow = out + ((size_t)b * NG + g) * NP;
        #pragma unroll
        for (int pt = 0; pt < 7; ++pt)
            #pragma unroll
            for (int r = 0; r < 4; ++r) {
                int p = pt * 16 + lh * 4 + r;
                if (gok && p < NP) orow[p] = vals2[pt][r] * inv;
            }
    }
}

extern "C" void kernel_launch(void* const* d_in, const int* in_sizes, int n_in,
                              void* d_out, int out_size, void* d_ws, size_t ws_size,
                              hipStream_t stream)
{
    const float* input1 = (const float*)d_in[0];
    const float* input2 = (const float*)d_in[1];
    const float* rem    = (const float*)d_in[2];
    const float* mask   = (const float*)d_in[3];
    const float* enc    = (const float*)d_in[4];
    const float* Wq     = (const float*)d_in[5];
    const float* Wk     = (const float*)d_in[6];
    const float* Wv     = (const float*)d_in[7];
    const float* Wc     = (const float*)d_in[8];
    const float* bc     = (const float*)d_in[9];

    short* WqT2 = (short*)d_ws;
    short* WkT  = WqT2 + 16384;
    short* WvT  = WkT + 16384;
    short* WcT  = WvT + 16384;

    prep_kernel<<<256, 256, 0, stream>>>(Wq, Wk, Wv, Wc, WqT2, WkT, WvT, WcT);

    hipFuncSetAttribute((const void*)fused_kernel,
                        hipFuncAttributeMaxDynamicSharedMemorySize, SMEM_BYTES);
    fused_kernel<<<NB, 448, SMEM_BYTES, stream>>>(
        input1, input2, rem, mask, enc, Wq, bc,
        WqT2, WkT, WvT, WcT, (float*)d_out);
}

// Round 3
// 247.141 us; speedup vs baseline: 1.3010x; 1.3010x over previous
//
#include <hip/hip_runtime.h>

#define NB 512
#define NG 100
#define NP 100
#define NE 128
#define NH 8

typedef __attribute__((ext_vector_type(8))) short short8;
typedef __attribute__((ext_vector_type(4))) short short4v;
typedef __attribute__((ext_vector_type(4))) float f32x4;

// LDS geometry: all bf16(short) row-major, XOR-swizzled per row.
// element (row,col) -> physical short offset: (row*STRIDE + col) ^ ((row&15)<<2)
#define SE_STRIDE 128
#define SK_STRIDE 128
#define SVT_STRIDE 112
#define SE_BASE 0
#define SK_BASE (100 * 128)                  // 12800 shorts
#define SVT_BASE (SK_BASE + 100 * 128)       // 25600 shorts
#define SMEM_SHORTS (SVT_BASE + 128 * 112)   // 39936 shorts = 79872 B
#define SMEM_BYTES (SMEM_SHORTS * 2 + 256 * 4)  // + sQ1[256] f32 = 80896 B

__device__ __forceinline__ short f2bf(float f) {
    union { float f; unsigned u; } v; v.f = f;
    unsigned r = v.u + 0x7FFFu + ((v.u >> 16) & 1u);
    return (short)(r >> 16);
}

__device__ __forceinline__ f32x4 mfma16(short4v a, short4v b, f32x4 c) {
#if __has_builtin(__builtin_amdgcn_mfma_f32_16x16x16_bf16)
    return __builtin_amdgcn_mfma_f32_16x16x16_bf16(a, b, c, 0, 0, 0);
#elif __has_builtin(__builtin_amdgcn_mfma_f32_16x16x16bf16_1k)
    return __builtin_amdgcn_mfma_f32_16x16x16bf16_1k(a, b, c, 0, 0, 0);
#else
    f32x4 d;
    asm volatile("v_mfma_f32_16x16x16_bf16 %0, %1, %2, %3"
                 : "=&v"(d) : "v"(a), "v"(b), "v"(c));
    return d;
#endif
}

__device__ __forceinline__ f32x4 mfma32(short8 a, short8 b, f32x4 c) {
    return __builtin_amdgcn_mfma_f32_16x16x32_bf16(a, b, c, 0, 0, 0);
}

// ---- prep: transpose weights to bf16 row-major [n][k] in ws ----
__global__ void prep_kernel(const float* __restrict__ Wq, const float* __restrict__ Wk,
                            const float* __restrict__ Wv, const float* __restrict__ Wc,
                            short* __restrict__ WqT2, short* __restrict__ WkT,
                            short* __restrict__ WvT, short* __restrict__ WcT)
{
    int idx = blockIdx.x * 256 + threadIdx.x;   // 65536 total
    int mat = idx >> 14;
    int e   = idx & 16383;
    int k = e >> 7, n = e & 127;
    float v;
    short* dst;
    if (mat == 0)      { v = Wq[(128 + k) * 128 + n]; dst = WqT2; }
    else if (mat == 1) { v = Wk[k * 128 + n];         dst = WkT;  }
    else if (mat == 2) { v = Wv[k * 128 + n];         dst = WvT;  }
    else               { v = Wc[k * 128 + n];         dst = WcT;  }
    dst[n * 128 + k] = f2bf(v);
}

// ---- fused main kernel: one block per batch, 7 waves, everything transposed ----
__global__ __launch_bounds__(448, 2)
void fused_kernel(const float* __restrict__ input1, const float* __restrict__ input2,
                  const float* __restrict__ rem, const float* __restrict__ mask,
                  const float* __restrict__ enc, const float* __restrict__ Wq,
                  const float* __restrict__ bc,
                  const short* __restrict__ WqT2, const short* __restrict__ WkT,
                  const short* __restrict__ WvT, const short* __restrict__ WcT,
                  float* __restrict__ out)
{
    extern __shared__ short smem[];
    float* sQ1 = (float*)(smem + SMEM_SHORTS);   // [2][128] q1 partials

    const int b    = blockIdx.x;
    const int tid  = threadIdx.x;
    const int wave = tid >> 6, lane = tid & 63;
    const int l16  = lane & 15, lh = lane >> 4;
    const int gt   = wave;                        // 7 waves, 7 g-tiles
    const int g    = gt * 16 + l16;
    const bool gok = (g < NG);
    const float NINF = -__builtin_inff();

    // ---------- Phase 0: stage enc -> sE (swizzled bf16), zero sVT pad, q1 ----------
    {
        const f32x4* e4 = (const f32x4*)(enc + (size_t)b * NP * NE);
        for (int idx = tid; idx < NP * 32; idx += 448) {
            int row = idx >> 5, c = idx & 31;
            f32x4 v = e4[idx];
            short4v h = { f2bf(v[0]), f2bf(v[1]), f2bf(v[2]), f2bf(v[3]) };
            int off = (row * SE_STRIDE + c * 4) ^ ((row & 15) << 2);
            *(short4v*)(smem + SE_BASE + off) = h;
        }
        // zero V^T cols 100..111 (never written afterwards)
        for (int idx = tid; idx < 128 * 3; idx += 448) {
            int row = idx / 3, c = 100 + (idx % 3) * 4;
            int off = (row * SVT_STRIDE + c) ^ ((row & 15) << 2);
            *(short4v*)(smem + SVT_BASE + off) = (short4v){0, 0, 0, 0};
        }
        // q1[n] = input1[b] . Wq[0:128, n] in two 64-k partials
        if (tid < 256) {
            int part = tid >> 7, n = tid & 127;
            const float* i1 = input1 + (size_t)b * NE + part * 64;
            const float* wq = Wq + (size_t)part * 64 * NE + n;
            float s = 0.f;
            #pragma unroll 8
            for (int k = 0; k < 64; ++k) s += i1[k] * wq[k * NE];
            sQ1[part * 128 + n] = s;
        }
    }
    __syncthreads();

    // ---------- Phase 1: Q^T into regs (x32), fold 1/sqrt(16), pack bf16 ----------
    // (first: its global input2 loads issue early, latency hides under phase 2)
    short4v qb[8];
    {
        const float* xrow = input2 + ((size_t)b * NG + g) * NE;
        short8 xb[4];
        #pragma unroll
        for (int ks = 0; ks < 4; ++ks) {
            f32x4 v0 = {0.f,0.f,0.f,0.f}, v1 = {0.f,0.f,0.f,0.f};
            if (gok) {
                v0 = *(const f32x4*)(xrow + ks * 32 + lh * 8);
                v1 = *(const f32x4*)(xrow + ks * 32 + lh * 8 + 4);
            }
            xb[ks] = (short8){ f2bf(v0[0]), f2bf(v0[1]), f2bf(v0[2]), f2bf(v0[3]),
                               f2bf(v1[0]), f2bf(v1[1]), f2bf(v1[2]), f2bf(v1[3]) };
        }
        float remv = gok ? rem[(size_t)b * NG + g] : 0.f;
        #pragma unroll
        for (int nt = 0; nt < 8; ++nt) {
            f32x4 acc = {0.f, 0.f, 0.f, 0.f};
            #pragma unroll
            for (int ks = 0; ks < 4; ++ks) {
                short8 a = *(const short8*)(WqT2 + (nt * 16 + l16) * NE + ks * 32 + lh * 8);
                acc = mfma32(a, xb[ks], acc);
            }
            f32x4 q1a = *(const f32x4*)(sQ1 + nt * 16 + lh * 4);
            f32x4 q1b = *(const f32x4*)(sQ1 + 128 + nt * 16 + lh * 4);
            f32x4 wlv = *(const f32x4*)(Wq + 256 * NE + nt * 16 + lh * 4);
            short4v q;
            #pragma unroll
            for (int r = 0; r < 4; ++r)
                q[r] = f2bf(0.25f * (acc[r] + q1a[r] + q1b[r] + remv * wlv[r]));
            qb[nt] = q;
        }
    }

    // ---------- Phase 2: K -> sK, V^T -> sVT (112 tile-tasks over 7 waves) ----------
    for (int t = wave; t < 112; t += 7) {
        int mat = (t >= 56);
        int tt  = mat ? t - 56 : t;
        int mt = tt >> 3, nt = tt & 7;
        const short* WT = mat ? WvT : WkT;
        int arow = mt * 16 + l16;
        bool aok = (arow < NP);
        f32x4 acc = {0.f, 0.f, 0.f, 0.f};
        #pragma unroll
        for (int kt = 0; kt < 8; ++kt) {
            short4v a = {0, 0, 0, 0};
            if (aok) {
                int off = (arow * SE_STRIDE + kt * 16 + lh * 4) ^ ((arow & 15) << 2);
                a = *(const short4v*)(smem + SE_BASE + off);
            }
            short4v w = *(const short4v*)(WT + (nt * 16 + l16) * NE + kt * 16 + lh * 4);
            acc = mfma16(a, w, acc);
        }
        if (!mat) {
            #pragma unroll
            for (int r = 0; r < 4; ++r) {
                int p = mt * 16 + lh * 4 + r;
                if (p < NP) {
                    int off = (p * SK_STRIDE + nt * 16 + l16) ^ ((p & 15) << 2);
                    smem[SK_BASE + off] = f2bf(acc[r]);
                }
            }
        } else {
            int vrow = nt * 16 + l16;          // k-dim 0..127
            int p0 = mt * 16 + lh * 4;
            if (p0 < NP) {                     // p0 in {..,96}: cols 96..99 valid
                short4v h = { f2bf(acc[0]), f2bf(acc[1]), f2bf(acc[2]), f2bf(acc[3]) };
                int off = (vrow * SVT_STRIDE + p0) ^ ((vrow & 15) << 2);
                *(short4v*)(smem + SVT_BASE + off) = h;
            }
        }
    }

    // ---------- mask preload (latency hidden by barrier wait) ----------
    float mk[7][4];
    {
        const float* mrow = mask + ((size_t)b * NG + g) * NP;
        #pragma unroll
        for (int pt = 0; pt < 7; ++pt)
            #pragma unroll
            for (int r = 0; r < 4; ++r) {
                int p = pt * 16 + lh * 4 + r;
                mk[pt][r] = (gok && p < NP) ? mrow[p] : NINF;
            }
    }
    __syncthreads();

    // ---------- Phase 3: attention, all-register online path ----------
    short4v ocb[8];
    #pragma unroll
    for (int h = 0; h < NH; ++h) {
        float vals[7][4];
        float m = NINF;
        #pragma unroll
        for (int pt = 0; pt < 7; ++pt) {
            int prow = pt * 16 + l16;
            int off = (prow * SK_STRIDE + h * 16 + lh * 4) ^ ((prow & 15) << 2);
            short4v kf = *(const short4v*)(smem + SK_BASE + off);
            f32x4 z = {0.f, 0.f, 0.f, 0.f};
            f32x4 sc = mfma16(kf, qb[h], z);
            bool pv = (pt < 6) || (lh == 0);   // p < 100
            #pragma unroll
            for (int r = 0; r < 4; ++r) {
                float v = pv ? sc[r] + mk[pt][r] : NINF;
                vals[pt][r] = v;
                m = fmaxf(m, v);
            }
        }
        m = fmaxf(m, __shfl_xor(m, 16));
        m = fmaxf(m, __shfl_xor(m, 32));
        float s = 0.f;
        #pragma unroll
        for (int pt = 0; pt < 7; ++pt)
            #pragma unroll
            for (int r = 0; r < 4; ++r) {
                float e = __expf(vals[pt][r] - m);
                vals[pt][r] = e; s += e;
            }
        s += __shfl_xor(s, 16);
        s += __shfl_xor(s, 32);
        float inv = 1.f / s;
        f32x4 o = {0.f, 0.f, 0.f, 0.f};
        #pragma unroll
        for (int pt = 0; pt < 7; ++pt) {
            short4v pb = { f2bf(vals[pt][0] * inv), f2bf(vals[pt][1] * inv),
                           f2bf(vals[pt][2] * inv), f2bf(vals[pt][3] * inv) };
            int vrow = h * 16 + l16;
            int off = (vrow * SVT_STRIDE + pt * 16 + lh * 4) ^ ((vrow & 15) << 2);
            short4v vf = *(const short4v*)(smem + SVT_BASE + off);
            o = mfma16(vf, pb, o);
        }
        ocb[h] = (short4v){ f2bf(o[0]), f2bf(o[1]), f2bf(o[2]), f2bf(o[3]) };
    }

    // ---------- Phase 4: Mh^T = Wc^T . oc^T + bc, fold 1/sqrt(128), pack ----------
    short4v mhb[8];
    #pragma unroll
    for (int nt = 0; nt < 8; ++nt) {
        f32x4 acc = {0.f, 0.f, 0.f, 0.f};
        #pragma unroll
        for (int kt = 0; kt < 8; ++kt) {
            short4v a = *(const short4v*)(WcT + (nt * 16 + l16) * NE + kt * 16 + lh * 4);
            acc = mfma16(a, ocb[kt], acc);
        }
        f32x4 bcv = *(const f32x4*)(bc + nt * 16 + lh * 4);
        mhb[nt] = (short4v){ f2bf((acc[0] + bcv[0]) * 0.08838834764831845f),
                             f2bf((acc[1] + bcv[1]) * 0.08838834764831845f),
                             f2bf((acc[2] + bcv[2]) * 0.08838834764831845f),
                             f2bf((acc[3] + bcv[3]) * 0.08838834764831845f) };
    }

    // ---------- Phase 5: pointer scores + tanh clip + softmax -> out ----------
    const float* mrow = mask + ((size_t)b * NG + g) * NP;
    float vals2[7][4];
    #pragma unroll
    for (int pt = 0; pt < 7; ++pt) {
        int prow = pt * 16 + l16;
        f32x4 acc = {0.f, 0.f, 0.f, 0.f};
        #pragma unroll
        for (int kt = 0; kt < 8; ++kt) {
            int off = (prow * SE_STRIDE + kt * 16 + lh * 4) ^ ((prow & 15) << 2);
            short4v ef = *(const short4v*)(smem + SE_BASE + off);
            acc = mfma16(ef, mhb[kt], acc);
        }
        #pragma unroll
        for (int r = 0; r < 4; ++r) {
            int p = pt * 16 + lh * 4 + r;
            bool pv = gok && (p < NP);
            float mkv = pv ? mrow[p] : NINF;
            float x = acc[r];                              // already scaled
            float th = 1.f - 2.f / (__expf(2.f * x) + 1.f);
            vals2[pt][r] = pv ? 10.f * th + mkv : NINF;
        }
    }
    {
        float m = NINF;
        #pragma unroll
        for (int pt = 0; pt < 7; ++pt)
            #pragma unroll
            for (int r = 0; r < 4; ++r) m = fmaxf(m, vals2[pt][r]);
        m = fmaxf(m, __shfl_xor(m, 16));
        m = fmaxf(m, __shfl_xor(m, 32));
        float s = 0.f;
        #pragma unroll
        for (int pt = 0; pt < 7; ++pt)
            #pragma unroll
            for (int r = 0; r < 4; ++r) {
                float e = __expf(vals2[pt][r] - m);
                vals2[pt][r] = e; s += e;
            }
        s += __shfl_xor(s, 16);
        s += __shfl_xor(s, 32);
        float inv = 1.f / s;
        float* orow = out + ((size_t)b * NG + g) * NP;
        #pragma unroll
        for (int pt = 0; pt < 7; ++pt)
            #pragma unroll
            for (int r = 0; r < 4; ++r) {
                int p = pt * 16 + lh * 4 + r;
                if (gok && p < NP) orow[p] = vals2[pt][r] * inv;
            }
    }
}

extern "C" void kernel_launch(void* const* d_in, const int* in_sizes, int n_in,
                              void* d_out, int out_size, void* d_ws, size_t ws_size,
                              hipStream_t stream)
{
    const float* input1 = (const float*)d_in[0];
    const float* input2 = (const float*)d_in[1];
    const float* rem    = (const float*)d_in[2];
    const float* mask   = (const float*)d_in[3];
    const float* enc    = (const float*)d_in[4];
    const float* Wq     = (const float*)d_in[5];
    const float* Wk     = (const float*)d_in[6];
    const float* Wv     = (const float*)d_in[7];
    const float* Wc     = (const float*)d_in[8];
    const float* bc     = (const float*)d_in[9];

    short* WqT2 = (short*)d_ws;
    short* WkT  = WqT2 + 16384;
    short* WvT  = WkT + 16384;
    short* WcT  = WvT + 16384;

    prep_kernel<<<256, 256, 0, stream>>>(Wq, Wk, Wv, Wc, WqT2, WkT, WvT, WcT);

    hipFuncSetAttribute((const void*)fused_kernel,
                        hipFuncAttributeMaxDynamicSharedMemorySize, SMEM_BYTES);
    fused_kernel<<<NB, 448, SMEM_BYTES, stream>>>(
        input1, input2, rem, mask, enc, Wq, bc,
        WqT2, WkT, WvT, WcT, (float*)d_out);
}